// Round 1
// baseline (1005.482 us; speedup 1.0000x reference)
//
#include <hip/hip_runtime.h>
#include <math.h>

#define CH 128

__device__ __forceinline__ float seluf(float x) {
    const float scale = 1.0507009873554804934193349852946f;
    const float alpha = 1.6732632423543772848170429916717f;
    return x > 0.0f ? scale * x : scale * alpha * (__expf(x) - 1.0f);
}

__device__ __forceinline__ float lrelu(float x) {
    return x > 0.0f ? x : 0.2f * x;
}

// ---- CSR build -------------------------------------------------------------

__global__ void k_hist(const int* __restrict__ ei, int* __restrict__ counts, int E) {
    int stride = gridDim.x * blockDim.x;
    for (int j = blockIdx.x * blockDim.x + threadIdx.x; j < E; j += stride)
        atomicAdd(&counts[ei[E + j]], 1);   // row 1 of edge_index = dst
}

__global__ __launch_bounds__(1024) void k_scan(const int* __restrict__ counts,
                                               int* __restrict__ rowptr, int n) {
    const int T = 1024;
    int t = threadIdx.x;
    int per = (n + T - 1) / T;
    int beg = t * per;
    int end = beg + per; if (end > n) end = n; if (beg > n) beg = n;
    int sum = 0;
    for (int i = beg; i < end; ++i) sum += counts[i] + 1;   // +1 self loop
    __shared__ int sbuf[T];
    sbuf[t] = sum;
    __syncthreads();
    for (int off = 1; off < T; off <<= 1) {
        int v = (t >= off) ? sbuf[t - off] : 0;
        __syncthreads();
        sbuf[t] += v;
        __syncthreads();
    }
    int run = sbuf[t] - sum;     // exclusive prefix
    for (int i = beg; i < end; ++i) { rowptr[i] = run; run += counts[i] + 1; }
    if (t == T - 1) rowptr[n] = run;
}

__global__ void k_scatter(const int* __restrict__ ei, const int* __restrict__ rowptr,
                          int* __restrict__ fill, int* __restrict__ csr, int n, int E) {
    int stride = gridDim.x * blockDim.x;
    int t0 = blockIdx.x * blockDim.x + threadIdx.x;
    for (int i = t0; i < n; i += stride) csr[rowptr[i]] = i;          // self loop slot
    for (int j = t0; j < E; j += stride) {
        int s = ei[j], d = ei[E + j];
        int pos = rowptr[d] + 1 + atomicAdd(&fill[d], 1);
        csr[pos] = s;
    }
}

// ---- GEMM (h = x@W) + fused attention dot products -------------------------
// 128 threads/block, thread c owns output column c; W column held in VGPRs.

__global__ __launch_bounds__(128) void k_gemm(
    const float* __restrict__ x, const float* __restrict__ W,
    const float* __restrict__ a_s, const float* __restrict__ a_d,
    float* __restrict__ h, float* __restrict__ as_o, float* __restrict__ ad_o, int n) {
    const int c = threadIdx.x;
    float w[CH];
#pragma unroll
    for (int k = 0; k < CH; ++k) w[k] = W[k * CH + c];
    float asc = a_s[c], adc = a_d[c];
    __shared__ float xs[4 * CH];
    __shared__ float redA[2][4], redD[2][4];
    const int wid = c >> 6, lane = c & 63;
    for (int r0 = blockIdx.x * 4; r0 < n; r0 += gridDim.x * 4) {
#pragma unroll
        for (int t = 0; t < 4; ++t) xs[t * CH + c] = x[(size_t)(r0 + t) * CH + c];
        __syncthreads();
        float acc[4] = {0.f, 0.f, 0.f, 0.f};
#pragma unroll
        for (int k4 = 0; k4 < CH / 4; ++k4) {
#pragma unroll
            for (int j = 0; j < 4; ++j) {
                float4 xv = ((const float4*)(xs + j * CH))[k4];
                acc[j] += xv.x * w[k4 * 4 + 0] + xv.y * w[k4 * 4 + 1] +
                          xv.z * w[k4 * 4 + 2] + xv.w * w[k4 * 4 + 3];
            }
        }
#pragma unroll
        for (int j = 0; j < 4; ++j) {
            h[(size_t)(r0 + j) * CH + c] = acc[j];
            float pa = acc[j] * asc, pd = acc[j] * adc;
#pragma unroll
            for (int o = 32; o > 0; o >>= 1) {
                pa += __shfl_xor(pa, o);
                pd += __shfl_xor(pd, o);
            }
            if (lane == 0) { redA[wid][j] = pa; redD[wid][j] = pd; }
        }
        __syncthreads();
        if (c < 4) {
            as_o[r0 + c] = redA[0][c] + redA[1][c];
            ad_o[r0 + c] = redD[0][c] + redD[1][c];
        }
        __syncthreads();
    }
}

// ---- per-node softmax over incoming edges ----------------------------------

__global__ void k_attn(const int* __restrict__ rowptr, const int* __restrict__ csr,
                       const float* __restrict__ as_v, const float* __restrict__ ad_v,
                       float* __restrict__ wedge, int n) {
    int i = blockIdx.x * blockDim.x + threadIdx.x;
    if (i >= n) return;
    int beg = rowptr[i], end = rowptr[i + 1];
    float adi = ad_v[i];
    float m = -1e30f;
    for (int p = beg; p < end; ++p) {
        float e = lrelu(as_v[csr[p]] + adi);
        wedge[p] = e;
        m = fmaxf(m, e);
    }
    float s = 0.f;
    for (int p = beg; p < end; ++p) {
        float wv = __expf(wedge[p] - m);
        s += wv;
        wedge[p] = wv;
    }
    float inv = 1.0f / s;
    for (int p = beg; p < end; ++p) wedge[p] *= inv;
}

// ---- aggregation: out[i] = selu( sum_j alpha_j * h[src_j] + b ) ------------
// one wave per node, lane l owns channels 2l, 2l+1.

__global__ __launch_bounds__(256) void k_agg(
    const int* __restrict__ rowptr, const int* __restrict__ csr,
    const float* __restrict__ wedge, const float* __restrict__ h,
    const float* __restrict__ bias, float* __restrict__ out, int n) {
    int gw = (int)((blockIdx.x * (size_t)blockDim.x + threadIdx.x) >> 6);
    int lane = threadIdx.x & 63;
    if (gw >= n) return;
    int beg = rowptr[gw], end = rowptr[gw + 1];
    float ax = 0.f, ay = 0.f;
    for (int p = beg; p < end; ++p) {
        int s = csr[p];
        float wv = wedge[p];
        float2 hv = ((const float2*)h)[(size_t)s * 64 + lane];
        ax += wv * hv.x;
        ay += wv * hv.y;
    }
    float ox = seluf(ax + bias[2 * lane]);
    float oy = seluf(ay + bias[2 * lane + 1]);
    ((float2*)out)[(size_t)gw * 64 + lane] = make_float2(ox, oy);
}

// ---- global mean pool (batch is sorted) ------------------------------------

__device__ int lower_bound_dev(const int* a, int n, int key) {
    int lo = 0, hi = n;
    while (lo < hi) {
        int mid = (lo + hi) >> 1;
        if (a[mid] < key) lo = mid + 1; else hi = mid;
    }
    return lo;
}

__global__ __launch_bounds__(256) void k_pool(const float* __restrict__ x,
                                              const int* __restrict__ batchv,
                                              float* __restrict__ outp, int n) {
    int g = blockIdx.x;
    int lo = lower_bound_dev(batchv, n, g);
    int hi = lower_bound_dev(batchv, n, g + 1);
    int lane = threadIdx.x & 63, wv = threadIdx.x >> 6;
    float sx = 0.f, sy = 0.f;
    for (int i = lo + wv; i < hi; i += 4) {
        float2 v = ((const float2*)x)[(size_t)i * 64 + lane];
        sx += v.x;
        sy += v.y;
    }
    __shared__ float2 red[4][64];
    red[wv][lane] = make_float2(sx, sy);
    __syncthreads();
    if (wv == 0) {
        float2 a = red[0][lane], b = red[1][lane], c = red[2][lane], d = red[3][lane];
        int cntv = hi - lo; if (cntv < 1) cntv = 1;
        float inv = 1.0f / (float)cntv;
        outp[(size_t)g * CH + 2 * lane] = (a.x + b.x + c.x + d.x) * inv;
        outp[(size_t)g * CH + 2 * lane + 1] = (a.y + b.y + c.y + d.y) * inv;
    }
}

// ---- orchestration ---------------------------------------------------------

extern "C" void kernel_launch(void* const* d_in, const int* in_sizes, int n_in,
                              void* d_out, int out_size, void* d_ws, size_t ws_size,
                              hipStream_t stream) {
    const float* u   = (const float*)d_in[0];
    const float* W1  = (const float*)d_in[1];
    const float* as1 = (const float*)d_in[2];
    const float* ad1 = (const float*)d_in[3];
    const float* b1  = (const float*)d_in[4];
    const float* W2  = (const float*)d_in[5];
    const float* as2 = (const float*)d_in[6];
    const float* ad2 = (const float*)d_in[7];
    const float* b2  = (const float*)d_in[8];
    const int* ei    = (const int*)d_in[9];
    const int* batchv= (const int*)d_in[10];

    const int N = in_sizes[0] / CH;
    const int E = in_sizes[9] / 2;
    const int M = E + N;

    char* p = (char*)d_ws;
    auto alloc = [&](size_t bytes) {
        char* r = p;
        p += (bytes + 255) & ~(size_t)255;
        return r;
    };
    int*   counts = (int*)alloc((size_t)N * 4);
    int*   fill   = (int*)alloc((size_t)N * 4);
    size_t zbytes = (size_t)(p - (char*)d_ws);      // zero counts+fill
    int*   rowptr = (int*)alloc((size_t)(N + 1) * 4);
    int*   csr    = (int*)alloc((size_t)M * 4);
    float* wedge  = (float*)alloc((size_t)M * 4);
    float* asv    = (float*)alloc((size_t)N * 4);
    float* adv    = (float*)alloc((size_t)N * 4);
    float* h      = (float*)alloc((size_t)N * CH * 4);
    float* x2     = (float*)alloc((size_t)N * CH * 4);

    hipMemsetAsync(d_ws, 0, zbytes, stream);

    k_hist<<<2048, 256, 0, stream>>>(ei, counts, E);
    k_scan<<<1, 1024, 0, stream>>>(counts, rowptr, N);
    k_scatter<<<2048, 256, 0, stream>>>(ei, rowptr, fill, csr, N, E);

    // layer 1
    k_gemm<<<1024, 128, 0, stream>>>(u, W1, as1, ad1, h, asv, adv, N);
    k_attn<<<(N + 255) / 256, 256, 0, stream>>>(rowptr, csr, asv, adv, wedge, N);
    k_agg<<<(N * 64 + 255) / 256, 256, 0, stream>>>(rowptr, csr, wedge, h, b1, x2, N);

    // layer 2
    k_gemm<<<1024, 128, 0, stream>>>(x2, W2, as2, ad2, h, asv, adv, N);
    k_attn<<<(N + 255) / 256, 256, 0, stream>>>(rowptr, csr, asv, adv, wedge, N);
    k_agg<<<(N * 64 + 255) / 256, 256, 0, stream>>>(rowptr, csr, wedge, h, b2, x2, N);

    k_pool<<<64, 256, 0, stream>>>(x2, batchv, (float*)d_out, N);
}

// Round 2
// 823.000 us; speedup vs baseline: 1.2217x; 1.2217x over previous
//
#include <hip/hip_runtime.h>
#include <math.h>

#define CH 128

__device__ __forceinline__ float seluf(float x) {
    const float scale = 1.0507009873554804934193349852946f;
    const float alpha = 1.6732632423543772848170429916717f;
    return x > 0.0f ? scale * x : scale * alpha * (__expf(x) - 1.0f);
}

__device__ __forceinline__ float lrelu(float x) {
    return x > 0.0f ? x : 0.2f * x;
}

// ---- CSR build -------------------------------------------------------------

__global__ void k_hist(const int* __restrict__ ei, int* __restrict__ counts, int E) {
    int stride = gridDim.x * blockDim.x;
    for (int j = blockIdx.x * blockDim.x + threadIdx.x; j < E; j += stride)
        atomicAdd(&counts[ei[E + j]], 1);   // row 1 of edge_index = dst
}

__global__ __launch_bounds__(1024) void k_scan(const int* __restrict__ counts,
                                               int* __restrict__ rowptr, int n) {
    const int T = 1024;
    int t = threadIdx.x;
    int per = (n + T - 1) / T;
    int beg = t * per;
    int end = beg + per; if (end > n) end = n; if (beg > n) beg = n;
    int sum = 0;
    for (int i = beg; i < end; ++i) sum += counts[i] + 1;   // +1 self loop
    __shared__ int sbuf[T];
    sbuf[t] = sum;
    __syncthreads();
    for (int off = 1; off < T; off <<= 1) {
        int v = (t >= off) ? sbuf[t - off] : 0;
        __syncthreads();
        sbuf[t] += v;
        __syncthreads();
    }
    int run = sbuf[t] - sum;     // exclusive prefix
    for (int i = beg; i < end; ++i) { rowptr[i] = run; run += counts[i] + 1; }
    if (t == T - 1) rowptr[n] = run;
}

__global__ void k_scatter(const int* __restrict__ ei, const int* __restrict__ rowptr,
                          int* __restrict__ fill, int* __restrict__ csr, int n, int E) {
    int stride = gridDim.x * blockDim.x;
    int t0 = blockIdx.x * blockDim.x + threadIdx.x;
    for (int i = t0; i < n; i += stride) csr[rowptr[i]] = i;          // self loop slot
    for (int j = t0; j < E; j += stride) {
        int s = ei[j], d = ei[E + j];
        int pos = rowptr[d] + 1 + atomicAdd(&fill[d], 1);
        csr[pos] = s;
    }
}

// ---- GEMM (h = x@W) + fused attention dot products -------------------------
// 128 threads/block, thread c owns output column c; W column held in VGPRs.

__global__ __launch_bounds__(128) void k_gemm(
    const float* __restrict__ x, const float* __restrict__ W,
    const float* __restrict__ a_s, const float* __restrict__ a_d,
    float* __restrict__ h, float* __restrict__ as_o, float* __restrict__ ad_o, int n) {
    const int c = threadIdx.x;
    float w[CH];
#pragma unroll
    for (int k = 0; k < CH; ++k) w[k] = W[k * CH + c];
    float asc = a_s[c], adc = a_d[c];
    __shared__ float xs[4 * CH];
    __shared__ float redA[2][4], redD[2][4];
    const int wid = c >> 6, lane = c & 63;
    for (int r0 = blockIdx.x * 4; r0 < n; r0 += gridDim.x * 4) {
#pragma unroll
        for (int t = 0; t < 4; ++t) xs[t * CH + c] = x[(size_t)(r0 + t) * CH + c];
        __syncthreads();
        float acc[4] = {0.f, 0.f, 0.f, 0.f};
#pragma unroll
        for (int k4 = 0; k4 < CH / 4; ++k4) {
#pragma unroll
            for (int j = 0; j < 4; ++j) {
                float4 xv = ((const float4*)(xs + j * CH))[k4];
                acc[j] += xv.x * w[k4 * 4 + 0] + xv.y * w[k4 * 4 + 1] +
                          xv.z * w[k4 * 4 + 2] + xv.w * w[k4 * 4 + 3];
            }
        }
#pragma unroll
        for (int j = 0; j < 4; ++j) {
            h[(size_t)(r0 + j) * CH + c] = acc[j];
            float pa = acc[j] * asc, pd = acc[j] * adc;
#pragma unroll
            for (int o = 32; o > 0; o >>= 1) {
                pa += __shfl_xor(pa, o);
                pd += __shfl_xor(pd, o);
            }
            if (lane == 0) { redA[wid][j] = pa; redD[wid][j] = pd; }
        }
        __syncthreads();
        if (c < 4) {
            as_o[r0 + c] = redA[0][c] + redA[1][c];
            ad_o[r0 + c] = redD[0][c] + redD[1][c];
        }
        __syncthreads();
    }
}

// ---- fused softmax + aggregation: one wave per node ------------------------
// Phase A: edge-parallel e=lrelu(as[src]+ad[i]), wave-max.
// Phase B: edge-parallel w=exp(e-m), wave-sum (denom folded into epilogue).
// Phase C: channel-parallel float4 gather, 2 edges/iter (half-wave each).

__global__ __launch_bounds__(256) void k_fused_agg(
    const int* __restrict__ rowptr, const int* __restrict__ csr,
    const float* __restrict__ as_v, const float* __restrict__ ad_v,
    float* __restrict__ wedge, const float* __restrict__ h,
    const float* __restrict__ bias, float* __restrict__ out, int n) {
    int gw = (int)((blockIdx.x * (size_t)blockDim.x + threadIdx.x) >> 6);
    int lane = threadIdx.x & 63;
    if (gw >= n) return;
    int beg = rowptr[gw], end = rowptr[gw + 1];
    float adi = ad_v[gw];

    // Phase A: scores + max (coalesced wedge writes: p contiguous across lanes)
    float m = -1e30f;
    for (int p = beg + lane; p < end; p += 64) {
        float e = lrelu(as_v[csr[p]] + adi);
        wedge[p] = e;
        m = fmaxf(m, e);
    }
#pragma unroll
    for (int o = 32; o > 0; o >>= 1) m = fmaxf(m, __shfl_xor(m, o));

    // Phase B: exp + denom
    float s = 0.f;
    for (int p = beg + lane; p < end; p += 64) {
        float wv = __expf(wedge[p] - m);
        wedge[p] = wv;
        s += wv;
    }
#pragma unroll
    for (int o = 32; o > 0; o >>= 1) s += __shfl_xor(s, o);
    float inv = 1.0f / s;

    // Phase C: gather-accumulate, 2 edges per iteration, float4 per lane
    const int half = lane >> 5;        // 0: edge p, 1: edge p+1
    const int c4 = lane & 31;          // channel block (4 floats)
    float4 acc = make_float4(0.f, 0.f, 0.f, 0.f);
    for (int p = beg; p < end; p += 2) {
        int pp = p + half;
        float wv;
        int src;
        if (pp < end) { wv = wedge[pp]; src = csr[pp]; }
        else { wv = 0.f; src = 0; }
        float4 hv = ((const float4*)h)[(size_t)src * 32 + c4];
        acc.x += wv * hv.x;
        acc.y += wv * hv.y;
        acc.z += wv * hv.z;
        acc.w += wv * hv.w;
    }
    acc.x += __shfl_xor(acc.x, 32);
    acc.y += __shfl_xor(acc.y, 32);
    acc.z += __shfl_xor(acc.z, 32);
    acc.w += __shfl_xor(acc.w, 32);
    if (half == 0) {
        float4 bv = ((const float4*)bias)[c4];
        float4 o;
        o.x = seluf(acc.x * inv + bv.x);
        o.y = seluf(acc.y * inv + bv.y);
        o.z = seluf(acc.z * inv + bv.z);
        o.w = seluf(acc.w * inv + bv.w);
        ((float4*)out)[(size_t)gw * 32 + c4] = o;
    }
}

// ---- global mean pool (batch is sorted) ------------------------------------

__device__ int lower_bound_dev(const int* a, int n, int key) {
    int lo = 0, hi = n;
    while (lo < hi) {
        int mid = (lo + hi) >> 1;
        if (a[mid] < key) lo = mid + 1; else hi = mid;
    }
    return lo;
}

__global__ __launch_bounds__(256) void k_pool(const float* __restrict__ x,
                                              const int* __restrict__ batchv,
                                              float* __restrict__ outp, int n) {
    int g = blockIdx.x;
    int lo = lower_bound_dev(batchv, n, g);
    int hi = lower_bound_dev(batchv, n, g + 1);
    int lane = threadIdx.x & 63, wv = threadIdx.x >> 6;
    float sx = 0.f, sy = 0.f;
    for (int i = lo + wv; i < hi; i += 4) {
        float2 v = ((const float2*)x)[(size_t)i * 64 + lane];
        sx += v.x;
        sy += v.y;
    }
    __shared__ float2 red[4][64];
    red[wv][lane] = make_float2(sx, sy);
    __syncthreads();
    if (wv == 0) {
        float2 a = red[0][lane], b = red[1][lane], c = red[2][lane], d = red[3][lane];
        int cntv = hi - lo; if (cntv < 1) cntv = 1;
        float inv = 1.0f / (float)cntv;
        outp[(size_t)g * CH + 2 * lane] = (a.x + b.x + c.x + d.x) * inv;
        outp[(size_t)g * CH + 2 * lane + 1] = (a.y + b.y + c.y + d.y) * inv;
    }
}

// ---- orchestration ---------------------------------------------------------

extern "C" void kernel_launch(void* const* d_in, const int* in_sizes, int n_in,
                              void* d_out, int out_size, void* d_ws, size_t ws_size,
                              hipStream_t stream) {
    const float* u   = (const float*)d_in[0];
    const float* W1  = (const float*)d_in[1];
    const float* as1 = (const float*)d_in[2];
    const float* ad1 = (const float*)d_in[3];
    const float* b1  = (const float*)d_in[4];
    const float* W2  = (const float*)d_in[5];
    const float* as2 = (const float*)d_in[6];
    const float* ad2 = (const float*)d_in[7];
    const float* b2  = (const float*)d_in[8];
    const int* ei    = (const int*)d_in[9];
    const int* batchv= (const int*)d_in[10];

    const int N = in_sizes[0] / CH;
    const int E = in_sizes[9] / 2;
    const int M = E + N;

    char* p = (char*)d_ws;
    auto alloc = [&](size_t bytes) {
        char* r = p;
        p += (bytes + 255) & ~(size_t)255;
        return r;
    };
    int*   counts = (int*)alloc((size_t)N * 4);
    int*   fill   = (int*)alloc((size_t)N * 4);
    size_t zbytes = (size_t)(p - (char*)d_ws);      // zero counts+fill
    int*   rowptr = (int*)alloc((size_t)(N + 1) * 4);
    int*   csr    = (int*)alloc((size_t)M * 4);
    float* wedge  = (float*)alloc((size_t)M * 4);
    float* asv    = (float*)alloc((size_t)N * 4);
    float* adv    = (float*)alloc((size_t)N * 4);
    float* h      = (float*)alloc((size_t)N * CH * 4);
    float* x2     = (float*)alloc((size_t)N * CH * 4);

    hipMemsetAsync(d_ws, 0, zbytes, stream);

    k_hist<<<2048, 256, 0, stream>>>(ei, counts, E);
    k_scan<<<1, 1024, 0, stream>>>(counts, rowptr, N);
    k_scatter<<<2048, 256, 0, stream>>>(ei, rowptr, fill, csr, N, E);

    // layer 1
    k_gemm<<<1024, 128, 0, stream>>>(u, W1, as1, ad1, h, asv, adv, N);
    k_fused_agg<<<(N * 64 + 255) / 256, 256, 0, stream>>>(rowptr, csr, asv, adv, wedge, h, b1, x2, N);

    // layer 2
    k_gemm<<<1024, 128, 0, stream>>>(x2, W2, as2, ad2, h, asv, adv, N);
    k_fused_agg<<<(N * 64 + 255) / 256, 256, 0, stream>>>(rowptr, csr, asv, adv, wedge, h, b2, x2, N);

    k_pool<<<64, 256, 0, stream>>>(x2, batchv, (float*)d_out, N);
}

// Round 3
// 707.627 us; speedup vs baseline: 1.4209x; 1.1630x over previous
//
#include <hip/hip_runtime.h>
#include <math.h>

#define CH 128

__device__ __forceinline__ float seluf(float x) {
    const float scale = 1.0507009873554804934193349852946f;
    const float alpha = 1.6732632423543772848170429916717f;
    return x > 0.0f ? scale * x : scale * alpha * (__expf(x) - 1.0f);
}

__device__ __forceinline__ float lrelu(float x) {
    return x > 0.0f ? x : 0.2f * x;
}

// ---- CSR build -------------------------------------------------------------

__global__ void k_hist(const int* __restrict__ ei, int* __restrict__ counts, int E) {
    int stride = gridDim.x * blockDim.x;
    for (int j = blockIdx.x * blockDim.x + threadIdx.x; j < E; j += stride)
        atomicAdd(&counts[ei[E + j]], 1);   // row 1 of edge_index = dst
}

__global__ __launch_bounds__(1024) void k_scan(const int* __restrict__ counts,
                                               int* __restrict__ rowptr, int n) {
    const int T = 1024;
    int t = threadIdx.x;
    int per = (n + T - 1) / T;
    int beg = t * per;
    int end = beg + per; if (end > n) end = n; if (beg > n) beg = n;
    int sum = 0;
    for (int i = beg; i < end; ++i) sum += counts[i] + 1;   // +1 self loop
    __shared__ int sbuf[T];
    sbuf[t] = sum;
    __syncthreads();
    for (int off = 1; off < T; off <<= 1) {
        int v = (t >= off) ? sbuf[t - off] : 0;
        __syncthreads();
        sbuf[t] += v;
        __syncthreads();
    }
    int run = sbuf[t] - sum;     // exclusive prefix
    for (int i = beg; i < end; ++i) { rowptr[i] = run; run += counts[i] + 1; }
    if (t == T - 1) rowptr[n] = run;
}

__global__ void k_scatter(const int* __restrict__ ei, const int* __restrict__ rowptr,
                          int* __restrict__ fill, int* __restrict__ csr, int n, int E) {
    int stride = gridDim.x * blockDim.x;
    int t0 = blockIdx.x * blockDim.x + threadIdx.x;
    for (int i = t0; i < n; i += stride) csr[rowptr[i]] = i;          // self loop slot
    for (int j = t0; j < E; j += stride) {
        int s = ei[j], d = ei[E + j];
        int pos = rowptr[d] + 1 + atomicAdd(&fill[d], 1);
        csr[pos] = s;
    }
}

// ---- GEMM v2: h = x@W, fused attention dots --------------------------------
// W staged once in LDS as Wl[k4][c][j] (j = k within 4-chunk) so a lane's
// ds_read_b128 at (k4*2048 + c*16) bytes is contiguous-by-lane.
// Each wave: 8 rows x 128 cols; lane owns cols {lane, lane+64} (16 accs).
// Row addresses wave-uniform -> x loads scalarize (or broadcast; both fine).

__global__ __launch_bounds__(256) void k_gemm2(
    const float* __restrict__ x, const float* __restrict__ W,
    const float* __restrict__ a_s, const float* __restrict__ a_d,
    float* __restrict__ h, float* __restrict__ as_o, float* __restrict__ ad_o, int n) {
    __shared__ float Wl[CH * CH];
    const int tid = threadIdx.x;
    for (int i = tid; i < CH * CH; i += 256) {
        int k = i >> 7, c = i & 127;
        Wl[((k >> 2) << 9) + (c << 2) + (k & 3)] = W[i];
    }
    __syncthreads();
    const int lane = tid & 63;
    const int wid = __builtin_amdgcn_readfirstlane(tid >> 6);
    const float as0 = a_s[lane], as1 = a_s[lane + 64];
    const float ad0 = a_d[lane], ad1 = a_d[lane + 64];

    int r0 = blockIdx.x * 32 + wid * 8;
    if (r0 >= n) return;

    int rr[8];
#pragma unroll
    for (int j = 0; j < 8; ++j) rr[j] = (r0 + j < n) ? (r0 + j) : (n - 1);

    float acc0[8], acc1[8];
#pragma unroll
    for (int j = 0; j < 8; ++j) { acc0[j] = 0.f; acc1[j] = 0.f; }

#pragma unroll 4
    for (int k4 = 0; k4 < 32; ++k4) {
        float4 xv[8];
#pragma unroll
        for (int j = 0; j < 8; ++j)
            xv[j] = ((const float4*)(x + (size_t)rr[j] * CH))[k4];
        float4 w0 = *(const float4*)(Wl + (k4 << 9) + (lane << 2));
        float4 w1 = *(const float4*)(Wl + (k4 << 9) + ((lane + 64) << 2));
#pragma unroll
        for (int j = 0; j < 8; ++j) {
            acc0[j] += xv[j].x * w0.x + xv[j].y * w0.y + xv[j].z * w0.z + xv[j].w * w0.w;
            acc1[j] += xv[j].x * w1.x + xv[j].y * w1.y + xv[j].z * w1.z + xv[j].w * w1.w;
        }
    }

#pragma unroll
    for (int j = 0; j < 8; ++j) {
        int r = r0 + j;
        if (r >= n) break;
        float pa = acc0[j] * as0 + acc1[j] * as1;
        float pd = acc0[j] * ad0 + acc1[j] * ad1;
#pragma unroll
        for (int o = 32; o > 0; o >>= 1) {
            pa += __shfl_xor(pa, o);
            pd += __shfl_xor(pd, o);
        }
        h[(size_t)r * CH + lane] = acc0[j];
        h[(size_t)r * CH + 64 + lane] = acc1[j];
        if (lane == 0) { as_o[r] = pa; ad_o[r] = pd; }
    }
}

// ---- fused softmax + aggregation: one wave per node ------------------------

__global__ __launch_bounds__(256) void k_fused_agg(
    const int* __restrict__ rowptr, const int* __restrict__ csr,
    const float* __restrict__ as_v, const float* __restrict__ ad_v,
    float* __restrict__ wedge, const float* __restrict__ h,
    const float* __restrict__ bias, float* __restrict__ out, int n) {
    int gw = (int)((blockIdx.x * (size_t)blockDim.x + threadIdx.x) >> 6);
    int lane = threadIdx.x & 63;
    if (gw >= n) return;
    int beg = rowptr[gw], end = rowptr[gw + 1];
    float adi = ad_v[gw];

    // Phase A: scores + max (coalesced wedge writes)
    float m = -1e30f;
    for (int p = beg + lane; p < end; p += 64) {
        float e = lrelu(as_v[csr[p]] + adi);
        wedge[p] = e;
        m = fmaxf(m, e);
    }
#pragma unroll
    for (int o = 32; o > 0; o >>= 1) m = fmaxf(m, __shfl_xor(m, o));

    // Phase B: exp + denom
    float s = 0.f;
    for (int p = beg + lane; p < end; p += 64) {
        float wv = __expf(wedge[p] - m);
        wedge[p] = wv;
        s += wv;
    }
#pragma unroll
    for (int o = 32; o > 0; o >>= 1) s += __shfl_xor(s, o);
    float inv = 1.0f / s;

    // Phase C: gather-accumulate, 2 edges per iteration, float4 per lane
    const int half = lane >> 5;
    const int c4 = lane & 31;
    float4 acc = make_float4(0.f, 0.f, 0.f, 0.f);
    for (int p = beg; p < end; p += 2) {
        int pp = p + half;
        float wv;
        int src;
        if (pp < end) { wv = wedge[pp]; src = csr[pp]; }
        else { wv = 0.f; src = 0; }
        float4 hv = ((const float4*)h)[(size_t)src * 32 + c4];
        acc.x += wv * hv.x;
        acc.y += wv * hv.y;
        acc.z += wv * hv.z;
        acc.w += wv * hv.w;
    }
    acc.x += __shfl_xor(acc.x, 32);
    acc.y += __shfl_xor(acc.y, 32);
    acc.z += __shfl_xor(acc.z, 32);
    acc.w += __shfl_xor(acc.w, 32);
    if (half == 0) {
        float4 bv = ((const float4*)bias)[c4];
        float4 o;
        o.x = seluf(acc.x * inv + bv.x);
        o.y = seluf(acc.y * inv + bv.y);
        o.z = seluf(acc.z * inv + bv.z);
        o.w = seluf(acc.w * inv + bv.w);
        ((float4*)out)[(size_t)gw * 32 + c4] = o;
    }
}

// ---- global mean pool (batch is sorted) ------------------------------------

__device__ int lower_bound_dev(const int* a, int n, int key) {
    int lo = 0, hi = n;
    while (lo < hi) {
        int mid = (lo + hi) >> 1;
        if (a[mid] < key) lo = mid + 1; else hi = mid;
    }
    return lo;
}

__global__ __launch_bounds__(256) void k_pool(const float* __restrict__ x,
                                              const int* __restrict__ batchv,
                                              float* __restrict__ outp, int n) {
    int g = blockIdx.x;
    int lo = lower_bound_dev(batchv, n, g);
    int hi = lower_bound_dev(batchv, n, g + 1);
    int lane = threadIdx.x & 63, wv = threadIdx.x >> 6;
    float sx = 0.f, sy = 0.f;
    for (int i = lo + wv; i < hi; i += 4) {
        float2 v = ((const float2*)x)[(size_t)i * 64 + lane];
        sx += v.x;
        sy += v.y;
    }
    __shared__ float2 red[4][64];
    red[wv][lane] = make_float2(sx, sy);
    __syncthreads();
    if (wv == 0) {
        float2 a = red[0][lane], b = red[1][lane], c = red[2][lane], d = red[3][lane];
        int cntv = hi - lo; if (cntv < 1) cntv = 1;
        float inv = 1.0f / (float)cntv;
        outp[(size_t)g * CH + 2 * lane] = (a.x + b.x + c.x + d.x) * inv;
        outp[(size_t)g * CH + 2 * lane + 1] = (a.y + b.y + c.y + d.y) * inv;
    }
}

// ---- orchestration ---------------------------------------------------------

extern "C" void kernel_launch(void* const* d_in, const int* in_sizes, int n_in,
                              void* d_out, int out_size, void* d_ws, size_t ws_size,
                              hipStream_t stream) {
    const float* u   = (const float*)d_in[0];
    const float* W1  = (const float*)d_in[1];
    const float* as1 = (const float*)d_in[2];
    const float* ad1 = (const float*)d_in[3];
    const float* b1  = (const float*)d_in[4];
    const float* W2  = (const float*)d_in[5];
    const float* as2 = (const float*)d_in[6];
    const float* ad2 = (const float*)d_in[7];
    const float* b2  = (const float*)d_in[8];
    const int* ei    = (const int*)d_in[9];
    const int* batchv= (const int*)d_in[10];

    const int N = in_sizes[0] / CH;
    const int E = in_sizes[9] / 2;
    const int M = E + N;

    char* p = (char*)d_ws;
    auto alloc = [&](size_t bytes) {
        char* r = p;
        p += (bytes + 255) & ~(size_t)255;
        return r;
    };
    int*   counts = (int*)alloc((size_t)N * 4);
    int*   fill   = (int*)alloc((size_t)N * 4);
    size_t zbytes = (size_t)(p - (char*)d_ws);      // zero counts+fill
    int*   rowptr = (int*)alloc((size_t)(N + 1) * 4);
    int*   csr    = (int*)alloc((size_t)M * 4);
    float* wedge  = (float*)alloc((size_t)M * 4);
    float* asv    = (float*)alloc((size_t)N * 4);
    float* adv    = (float*)alloc((size_t)N * 4);
    float* h      = (float*)alloc((size_t)N * CH * 4);
    float* x2     = (float*)alloc((size_t)N * CH * 4);

    hipMemsetAsync(d_ws, 0, zbytes, stream);

    k_hist<<<2048, 256, 0, stream>>>(ei, counts, E);
    k_scan<<<1, 1024, 0, stream>>>(counts, rowptr, N);
    k_scatter<<<2048, 256, 0, stream>>>(ei, rowptr, fill, csr, N, E);

    const int gblocks = (N + 31) / 32;

    // layer 1
    k_gemm2<<<gblocks, 256, 0, stream>>>(u, W1, as1, ad1, h, asv, adv, N);
    k_fused_agg<<<(N * 64 + 255) / 256, 256, 0, stream>>>(rowptr, csr, asv, adv, wedge, h, b1, x2, N);

    // layer 2
    k_gemm2<<<gblocks, 256, 0, stream>>>(x2, W2, as2, ad2, h, asv, adv, N);
    k_fused_agg<<<(N * 64 + 255) / 256, 256, 0, stream>>>(rowptr, csr, asv, adv, wedge, h, b2, x2, N);

    k_pool<<<64, 256, 0, stream>>>(x2, batchv, (float*)d_out, N);
}

// Round 4
// 615.872 us; speedup vs baseline: 1.6326x; 1.1490x over previous
//
#include <hip/hip_runtime.h>
#include <hip/hip_bf16.h>
#include <math.h>

#define CH 128

__device__ __forceinline__ float seluf(float x) {
    const float scale = 1.0507009873554804934193349852946f;
    const float alpha = 1.6732632423543772848170429916717f;
    return x > 0.0f ? scale * x : scale * alpha * (__expf(x) - 1.0f);
}

__device__ __forceinline__ float lrelu(float x) {
    return x > 0.0f ? x : 0.2f * x;
}

// ---- CSR build -------------------------------------------------------------

__global__ void k_hist(const int* __restrict__ ei, int* __restrict__ counts, int E) {
    int stride = gridDim.x * blockDim.x;
    for (int j = blockIdx.x * blockDim.x + threadIdx.x; j < E; j += stride)
        atomicAdd(&counts[ei[E + j]], 1);   // row 1 of edge_index = dst
}

__global__ __launch_bounds__(1024) void k_scan(const int* __restrict__ counts,
                                               int* __restrict__ rowptr, int n) {
    const int T = 1024;
    int t = threadIdx.x;
    int per = (n + T - 1) / T;
    int beg = t * per;
    int end = beg + per; if (end > n) end = n; if (beg > n) beg = n;
    int sum = 0;
    for (int i = beg; i < end; ++i) sum += counts[i] + 1;   // +1 self loop
    __shared__ int sbuf[T];
    sbuf[t] = sum;
    __syncthreads();
    for (int off = 1; off < T; off <<= 1) {
        int v = (t >= off) ? sbuf[t - off] : 0;
        __syncthreads();
        sbuf[t] += v;
        __syncthreads();
    }
    int run = sbuf[t] - sum;     // exclusive prefix
    for (int i = beg; i < end; ++i) { rowptr[i] = run; run += counts[i] + 1; }
    if (t == T - 1) rowptr[n] = run;
}

__global__ void k_scatter(const int* __restrict__ ei, const int* __restrict__ rowptr,
                          int* __restrict__ fill, int* __restrict__ csr, int n, int E) {
    int stride = gridDim.x * blockDim.x;
    int t0 = blockIdx.x * blockDim.x + threadIdx.x;
    for (int i = t0; i < n; i += stride) csr[rowptr[i]] = i;          // self loop slot
    for (int j = t0; j < E; j += stride) {
        int s = ei[j], d = ei[E + j];
        int pos = rowptr[d] + 1 + atomicAdd(&fill[d], 1);
        csr[pos] = s;
    }
}

// ---- GEMM v2: h = x@W (bf16 out), fused attention dots ---------------------
// W staged once in LDS as Wl[k4][c][j]; each wave does 8 rows x 128 cols.

__global__ __launch_bounds__(256) void k_gemm2(
    const float* __restrict__ x, const float* __restrict__ W,
    const float* __restrict__ a_s, const float* __restrict__ a_d,
    __hip_bfloat16* __restrict__ hb, float* __restrict__ as_o,
    float* __restrict__ ad_o, int n) {
    __shared__ float Wl[CH * CH];
    const int tid = threadIdx.x;
    for (int i = tid; i < CH * CH; i += 256) {
        int k = i >> 7, c = i & 127;
        Wl[((k >> 2) << 9) + (c << 2) + (k & 3)] = W[i];
    }
    __syncthreads();
    const int lane = tid & 63;
    const int wid = __builtin_amdgcn_readfirstlane(tid >> 6);
    const float as0 = a_s[lane], as1 = a_s[lane + 64];
    const float ad0 = a_d[lane], ad1 = a_d[lane + 64];

    int r0 = blockIdx.x * 32 + wid * 8;
    if (r0 >= n) return;

    int rr[8];
#pragma unroll
    for (int j = 0; j < 8; ++j) rr[j] = (r0 + j < n) ? (r0 + j) : (n - 1);

    float acc0[8], acc1[8];
#pragma unroll
    for (int j = 0; j < 8; ++j) { acc0[j] = 0.f; acc1[j] = 0.f; }

#pragma unroll 4
    for (int k4 = 0; k4 < 32; ++k4) {
        float4 xv[8];
#pragma unroll
        for (int j = 0; j < 8; ++j)
            xv[j] = ((const float4*)(x + (size_t)rr[j] * CH))[k4];
        float4 w0 = *(const float4*)(Wl + (k4 << 9) + (lane << 2));
        float4 w1 = *(const float4*)(Wl + (k4 << 9) + ((lane + 64) << 2));
#pragma unroll
        for (int j = 0; j < 8; ++j) {
            acc0[j] += xv[j].x * w0.x + xv[j].y * w0.y + xv[j].z * w0.z + xv[j].w * w0.w;
            acc1[j] += xv[j].x * w1.x + xv[j].y * w1.y + xv[j].z * w1.z + xv[j].w * w1.w;
        }
    }

#pragma unroll
    for (int j = 0; j < 8; ++j) {
        int r = r0 + j;
        if (r >= n) break;
        float pa = acc0[j] * as0 + acc1[j] * as1;
        float pd = acc0[j] * ad0 + acc1[j] * ad1;
#pragma unroll
        for (int o = 32; o > 0; o >>= 1) {
            pa += __shfl_xor(pa, o);
            pd += __shfl_xor(pd, o);
        }
        hb[(size_t)r * CH + lane] = __float2bfloat16(acc0[j]);
        hb[(size_t)r * CH + 64 + lane] = __float2bfloat16(acc1[j]);
        if (lane == 0) { as_o[r] = pa; ad_o[r] = pd; }
    }
}

// ---- fused softmax + aggregation: one wave per node ------------------------
// Phase A/B: edge-parallel score/max then exp/denom (denom folded in epilogue).
// Phase C: 4 edges/iter; 16 lanes x 8 bf16 channels (16B gather per lane).

__global__ __launch_bounds__(256) void k_fused_agg(
    const int* __restrict__ rowptr, const int* __restrict__ csr,
    const float* __restrict__ as_v, const float* __restrict__ ad_v,
    float* __restrict__ wedge, const __hip_bfloat16* __restrict__ hb,
    const float* __restrict__ bias, float* __restrict__ out, int n) {
    int gw = (int)((blockIdx.x * (size_t)blockDim.x + threadIdx.x) >> 6);
    int lane = threadIdx.x & 63;
    if (gw >= n) return;
    int beg = rowptr[gw], end = rowptr[gw + 1];
    float adi = ad_v[gw];

    // Phase A: scores + max (coalesced wedge writes)
    float m = -1e30f;
    for (int p = beg + lane; p < end; p += 64) {
        float e = lrelu(as_v[csr[p]] + adi);
        wedge[p] = e;
        m = fmaxf(m, e);
    }
#pragma unroll
    for (int o = 32; o > 0; o >>= 1) m = fmaxf(m, __shfl_xor(m, o));

    // Phase B: exp + denom
    float s = 0.f;
    for (int p = beg + lane; p < end; p += 64) {
        float wv = __expf(wedge[p] - m);
        wedge[p] = wv;
        s += wv;
    }
#pragma unroll
    for (int o = 32; o > 0; o >>= 1) s += __shfl_xor(s, o);
    float inv = 1.0f / s;

    // Phase C: bf16 gather-accumulate, 4 edges per iteration
    const int quarter = lane >> 4;     // edge sub-slot 0..3
    const int c8 = lane & 15;          // 8-channel block
    float acc[8];
#pragma unroll
    for (int k = 0; k < 8; ++k) acc[k] = 0.f;
    for (int p = beg; p < end; p += 4) {
        int pp = p + quarter;
        float wv; int src;
        if (pp < end) { wv = wedge[pp]; src = csr[pp]; }
        else { wv = 0.f; src = 0; }
        uint4 hv = ((const uint4*)hb)[(size_t)src * 16 + c8];
        acc[0] += wv * __uint_as_float(hv.x << 16);
        acc[1] += wv * __uint_as_float(hv.x & 0xffff0000u);
        acc[2] += wv * __uint_as_float(hv.y << 16);
        acc[3] += wv * __uint_as_float(hv.y & 0xffff0000u);
        acc[4] += wv * __uint_as_float(hv.z << 16);
        acc[5] += wv * __uint_as_float(hv.z & 0xffff0000u);
        acc[6] += wv * __uint_as_float(hv.w << 16);
        acc[7] += wv * __uint_as_float(hv.w & 0xffff0000u);
    }
#pragma unroll
    for (int k = 0; k < 8; ++k) {
        acc[k] += __shfl_xor(acc[k], 16);
        acc[k] += __shfl_xor(acc[k], 32);
    }
    if (quarter == 0) {
        const float4 bv0 = ((const float4*)bias)[c8 * 2];
        const float4 bv1 = ((const float4*)bias)[c8 * 2 + 1];
        float4 o0, o1;
        o0.x = seluf(acc[0] * inv + bv0.x);
        o0.y = seluf(acc[1] * inv + bv0.y);
        o0.z = seluf(acc[2] * inv + bv0.z);
        o0.w = seluf(acc[3] * inv + bv0.w);
        o1.x = seluf(acc[4] * inv + bv1.x);
        o1.y = seluf(acc[5] * inv + bv1.y);
        o1.z = seluf(acc[6] * inv + bv1.z);
        o1.w = seluf(acc[7] * inv + bv1.w);
        ((float4*)out)[(size_t)gw * 32 + c8 * 2] = o0;
        ((float4*)out)[(size_t)gw * 32 + c8 * 2 + 1] = o1;
    }
}

// ---- global mean pool (batch is sorted) ------------------------------------

__device__ int lower_bound_dev(const int* a, int n, int key) {
    int lo = 0, hi = n;
    while (lo < hi) {
        int mid = (lo + hi) >> 1;
        if (a[mid] < key) lo = mid + 1; else hi = mid;
    }
    return lo;
}

__global__ __launch_bounds__(256) void k_pool(const float* __restrict__ x,
                                              const int* __restrict__ batchv,
                                              float* __restrict__ outp, int n) {
    int g = blockIdx.x;
    int lo = lower_bound_dev(batchv, n, g);
    int hi = lower_bound_dev(batchv, n, g + 1);
    int lane = threadIdx.x & 63, wv = threadIdx.x >> 6;
    float sx = 0.f, sy = 0.f;
    for (int i = lo + wv; i < hi; i += 4) {
        float2 v = ((const float2*)x)[(size_t)i * 64 + lane];
        sx += v.x;
        sy += v.y;
    }
    __shared__ float2 red[4][64];
    red[wv][lane] = make_float2(sx, sy);
    __syncthreads();
    if (wv == 0) {
        float2 a = red[0][lane], b = red[1][lane], c = red[2][lane], d = red[3][lane];
        int cntv = hi - lo; if (cntv < 1) cntv = 1;
        float inv = 1.0f / (float)cntv;
        outp[(size_t)g * CH + 2 * lane] = (a.x + b.x + c.x + d.x) * inv;
        outp[(size_t)g * CH + 2 * lane + 1] = (a.y + b.y + c.y + d.y) * inv;
    }
}

// ---- orchestration ---------------------------------------------------------

extern "C" void kernel_launch(void* const* d_in, const int* in_sizes, int n_in,
                              void* d_out, int out_size, void* d_ws, size_t ws_size,
                              hipStream_t stream) {
    const float* u   = (const float*)d_in[0];
    const float* W1  = (const float*)d_in[1];
    const float* as1 = (const float*)d_in[2];
    const float* ad1 = (const float*)d_in[3];
    const float* b1  = (const float*)d_in[4];
    const float* W2  = (const float*)d_in[5];
    const float* as2 = (const float*)d_in[6];
    const float* ad2 = (const float*)d_in[7];
    const float* b2  = (const float*)d_in[8];
    const int* ei    = (const int*)d_in[9];
    const int* batchv= (const int*)d_in[10];

    const int N = in_sizes[0] / CH;
    const int E = in_sizes[9] / 2;
    const int M = E + N;

    char* p = (char*)d_ws;
    auto alloc = [&](size_t bytes) {
        char* r = p;
        p += (bytes + 255) & ~(size_t)255;
        return r;
    };
    int*   counts = (int*)alloc((size_t)N * 4);
    int*   fill   = (int*)alloc((size_t)N * 4);
    size_t zbytes = (size_t)(p - (char*)d_ws);      // zero counts+fill
    int*   rowptr = (int*)alloc((size_t)(N + 1) * 4);
    int*   csr    = (int*)alloc((size_t)M * 4);
    float* wedge  = (float*)alloc((size_t)M * 4);
    float* asv    = (float*)alloc((size_t)N * 4);
    float* adv    = (float*)alloc((size_t)N * 4);
    __hip_bfloat16* hbuf = (__hip_bfloat16*)alloc((size_t)N * CH * 2);
    float* x2     = (float*)alloc((size_t)N * CH * 4);

    hipMemsetAsync(d_ws, 0, zbytes, stream);

    k_hist<<<2048, 256, 0, stream>>>(ei, counts, E);
    k_scan<<<1, 1024, 0, stream>>>(counts, rowptr, N);
    k_scatter<<<2048, 256, 0, stream>>>(ei, rowptr, fill, csr, N, E);

    const int gblocks = (N + 31) / 32;

    // layer 1
    k_gemm2<<<gblocks, 256, 0, stream>>>(u, W1, as1, ad1, hbuf, asv, adv, N);
    k_fused_agg<<<(N * 64 + 255) / 256, 256, 0, stream>>>(rowptr, csr, asv, adv, wedge, hbuf, b1, x2, N);

    // layer 2
    k_gemm2<<<gblocks, 256, 0, stream>>>(x2, W2, as2, ad2, hbuf, asv, adv, N);
    k_fused_agg<<<(N * 64 + 255) / 256, 256, 0, stream>>>(rowptr, csr, asv, adv, wedge, hbuf, b2, x2, N);

    k_pool<<<64, 256, 0, stream>>>(x2, batchv, (float*)d_out, N);
}